// Round 3
// baseline (99.442 us; speedup 1.0000x reference)
//
#include <hip/hip_runtime.h>

// Problem constants
#define NVEC 65536      // B*R*C = 8*16*512
#define KDIM 64
#define SDIM 512

// Output layout (flat float32)
#define Z_OFF       4194304     // NVEC*KDIM
#define LCOMMIT_OFF 4259840
#define LCODE_OFF   4259841
#define E_OFF       4259842

typedef _Float16 half8    __attribute__((ext_vector_type(8)));
typedef float    floatx16 __attribute__((ext_vector_type(16)));

// R10: bisect round. R8/R9 (fused conversion + finish kernel) hit
// "container failed twice" twice; audit found no defect, so anchor back to
// the harness-verified R7 and apply ONLY the atomic-tail fix:
//   - vq_main: esum/atomic machinery deleted entirely (the 512 same-line
//     RMWs were a ~7us serialized TAIL: grid == co-resident capacity, all
//     blocks finish together, chain drains after compute).
//   - vq_finish (1 block x 1024): sums the already-written errs2 region of
//     `out` directly (no extra ws), writes LCOMMIT/LCODE. E_OFF is 8B- but
//     not 16B-aligned -> float2 loads.
// vq_prep and the vq_main core are byte-identical to R7.

// ws: c32 [SDIM*KDIM] f32, cnorm [SDIM] f32, cbf16 [SDIM*KDIM*2] f16
//
// cbf16 chunk layout (R4-verified): half index
//   (s>>5)*4096 + p*2048 + q*512 + h*256 + (s&31)*8 + j
// Tile t (128 codewords) = 32 KB contiguous at t*16384 halfs; within the tile
// the layout IS the LDS compute layout -> pure linear 16B DMA staging.

__global__ void vq_prep(const float* __restrict__ c_sum,
                        const float* __restrict__ c_count,
                        float* __restrict__ c32,
                        float* __restrict__ cnorm,
                        _Float16* __restrict__ cbf16) {
    int s = blockIdx.x;          // 0..511
    int k = threadIdx.x;         // 0..63
    float cnt = c_count[s];
    float inv = 1.0f / fmaxf(cnt, 0.01f);
    float x = c_sum[s * KDIM + k] * inv;
    c32[s * KDIM + k] = x;
    float sq = x * x;
    #pragma unroll
    for (int off = 32; off > 0; off >>= 1)
        sq += __shfl_down(sq, off);
    if (k == 0) cnorm[s] = sq;

    __shared__ _Float16 hb[64], lb[64];
    _Float16 hi = (_Float16)x;
    float hiF = (float)hi;
    _Float16 lo = (_Float16)(x - hiF);
    hb[k] = hi; lb[k] = lo;
    __syncthreads();
    if (k < 16) {
        int p  = k >> 3;
        int qh = k & 7;                       // q*2 + h
        int k0 = (qh >> 1) * 16 + (qh & 1) * 8;
        const _Float16* srcb = (p ? lb : hb) + k0;
        half8 v;
        #pragma unroll
        for (int j = 0; j < 8; ++j) v[j] = srcb[j];
        size_t chunk = ((size_t)(s >> 5) * 16 + p * 8 + qh) * 32 + (s & 31);
        *(half8*)(cbf16 + chunk * 8) = v;
    }
}

// 512 blocks x 256 threads (4 waves, M=32/wave). Double-buffered DMA staging.
__global__ __launch_bounds__(256, 2) void vq_main(const float* __restrict__ vecs,
                                                  const _Float16* __restrict__ cbf16,
                                                  const float* __restrict__ c32,
                                                  const float* __restrict__ cnorm,
                                                  float* __restrict__ out) {
    __shared__ __align__(16) _Float16 cw[2][16384];   // 2 x 32 KB B-tiles
    __shared__ float cnL[512];
    __shared__ float vnL[4][32];
    __shared__ int   zL[4][32];

    const int tx   = threadIdx.x;
    const int lane = tx & 63;
    const int w    = tx >> 6;
    const int col  = lane & 31;
    const int h    = lane >> 5;
    const int wvec = (int)blockIdx.x * 128 + w * 32;

    // async DMA of one 32 KB tile: wave w copies bytes [w*8K, w*8K+8K)
    // as 8 instructions x (64 lanes x 16 B). LDS dest = uniform base + lane*16.
    #define DMA_TILE(buf, t)                                                      \
    {                                                                             \
        const _Float16* _src = cbf16 + (size_t)(t) * 16384 + w * 4096 + lane * 8; \
        _Float16* _dst = &cw[buf][w * 4096 + lane * 8];                           \
        _Pragma("unroll")                                                         \
        for (int _i = 0; _i < 8; ++_i)                                            \
            __builtin_amdgcn_global_load_lds(                                     \
                (const __attribute__((address_space(1))) void*)(_src + _i * 512), \
                (__attribute__((address_space(3))) void*)(_dst + _i * 512),       \
                16, 0, 0);                                                        \
    }

    DMA_TILE(0, 0)   // tile 0 in flight during the whole prologue

    // ---- A fragments (hi/lo f16) + vnorm (R4/R5-verified tree) ----
    half8 ahi[4], alo[4];
    float vnp = 0.0f;
    const float* arow = vecs + (size_t)(wvec + col) * KDIM + h * 8;
    #pragma unroll
    for (int q = 0; q < 4; ++q) {
        float4 x0 = *(const float4*)(arow + q * 16);
        float4 x1 = *(const float4*)(arow + q * 16 + 4);
        #define CVT(X, J) { float xx = (X); _Float16 hi5 = (_Float16)xx; \
                            float hf = (float)hi5; ahi[q][J] = hi5; \
                            alo[q][J] = (_Float16)(xx - hf); vnp += xx * xx; }
        CVT(x0.x, 0) CVT(x0.y, 1) CVT(x0.z, 2) CVT(x0.w, 3)
        CVT(x1.x, 4) CVT(x1.y, 5) CVT(x1.z, 6) CVT(x1.w, 7)
        #undef CVT
    }
    vnp += __shfl_xor(vnp, 32);
    if (h == 0) vnL[w][col] = vnp;

    // whole cnorm into LDS once
    cnL[tx]       = cnorm[tx];
    cnL[tx + 256] = cnorm[tx + 256];

    // running argmax of m = -cn/2 + dot (== argmin dist; first-index ties)
    float bm[16];
    int   bi[16];
    #pragma unroll
    for (int r = 0; r < 16; ++r) { bm[r] = -3.4e38f; bi[r] = 0; }

    for (int t = 0; t < 4; ++t) {
        // barrier: (a) all waves past compute on buf[(t+1)&1], (b) compiler's
        // vmcnt(0)+lgkmcnt(0) drain => DMA for tile t landed & visible.
        __syncthreads();
        if (t < 3) DMA_TILE((t + 1) & 1, t + 1)   // in flight across compute(t)

        const _Float16* cwb = cw[t & 1];
        #pragma unroll
        for (int sub = 0; sub < 4; ++sub) {
            const _Float16* bb = cwb + sub * 4096 + lane * 8;
            float ci = -0.5f * cnL[t * 128 + sub * 32 + col];
            floatx16 a0, a1;
            #pragma unroll
            for (int r = 0; r < 16; ++r) { a0[r] = ci; a1[r] = 0.0f; }
            #pragma unroll
            for (int q = 0; q < 4; ++q) {
                half8 bh = *(const half8*)(bb + q * 512);
                half8 bl = *(const half8*)(bb + 2048 + q * 512);
                a0 = __builtin_amdgcn_mfma_f32_32x32x16_f16(ahi[q], bh, a0, 0, 0, 0);
                a1 = __builtin_amdgcn_mfma_f32_32x32x16_f16(alo[q], bh, a1, 0, 0, 0);
                a1 = __builtin_amdgcn_mfma_f32_32x32x16_f16(ahi[q], bl, a1, 0, 0, 0);
            }
            int n = t * 128 + sub * 32 + col;
            #pragma unroll
            for (int r = 0; r < 16; ++r) {
                float m = a0[r] + a1[r];
                if (m > bm[r]) { bm[r] = m; bi[r] = n; }   // strict >, increasing n
            }
        }
    }

    // ---- cross-lane argmax per row (32 cols; xor<=16 stays within h) ----
    #pragma unroll
    for (int r = 0; r < 16; ++r) {
        float v = bm[r]; int i = bi[r];
        #pragma unroll
        for (int off = 16; off > 0; off >>= 1) {
            float ov = __shfl_xor(v, off);
            int   oi = __shfl_xor(i, off);
            if (ov > v || (ov == v && oi < i)) { v = ov; i = oi; }
        }
        bm[r] = v; bi[r] = i;
    }

    if (col == 0) {
        #pragma unroll
        for (int r = 0; r < 16; ++r) {
            int row = (r & 3) + 8 * (r >> 2) + 4 * h;   // C/D row map (verified)
            int vid = wvec + row;
            float err = fmaxf(vnL[w][row] - 2.0f * bm[r], 0.0f);
            out[Z_OFF + vid] = (float)bi[r];
            out[E_OFF + vid] = err;
            zL[w][row] = bi[r];
        }
    }

    // ---- vecs_hat gather from c32 (R4-verified), coalesced float4 ----
    #pragma unroll
    for (int it = 0; it < 8; ++it) {
        int row = it * 4 + (lane >> 4);
        int c4  = lane & 15;
        int z   = zL[w][row];
        float4 val = *(const float4*)(c32 + (size_t)z * KDIM + c4 * 4);
        *(float4*)(out + (size_t)(wvec + row) * KDIM + c4 * 4) = val;
    }
    // R10: NO atomics, no esum here — vq_finish reduces out[E_OFF..] itself.
    #undef DMA_TILE
}

// 1 block x 1024 threads: sum the 65536 errs just written to out[E_OFF..],
// write both scalar losses. Replaces both the per-block atomic chain (a
// ~7us serialized tail in R4..R7) and vq_prep's zero-init duty.
// E_OFF is even but not 0 mod 4 -> 8B-aligned float2 loads only.
__global__ __launch_bounds__(1024) void vq_finish(float* __restrict__ out) {
    __shared__ float part[16];
    const int tx = threadIdx.x;
    const float2* e2 = (const float2*)(out + E_OFF);   // 32768 float2
    float s = 0.0f;
    #pragma unroll
    for (int k = 0; k < 32; ++k) {
        float2 v = e2[tx + k * 1024];
        s += v.x + v.y;
    }
    #pragma unroll
    for (int off = 32; off > 0; off >>= 1) s += __shfl_down(s, off);
    if ((tx & 63) == 0) part[tx >> 6] = s;
    __syncthreads();
    if (tx == 0) {
        float tot = 0.0f;
        #pragma unroll
        for (int i = 0; i < 16; ++i) tot += part[i];
        out[LCOMMIT_OFF] = tot * (1.0f / (float)NVEC);
        out[LCODE_OFF]   = 0.0f;
    }
}

extern "C" void kernel_launch(void* const* d_in, const int* in_sizes, int n_in,
                              void* d_out, int out_size, void* d_ws, size_t ws_size,
                              hipStream_t stream) {
    const float* vecs    = (const float*)d_in[0];  // [8,16,512,64]
    const float* c_sum   = (const float*)d_in[1];  // [512,64]
    const float* c_count = (const float*)d_in[2];  // [512]
    float* out = (float*)d_out;

    float*    c32   = (float*)d_ws;                      // 128 KB
    float*    cnorm = c32 + SDIM * KDIM;                 // 2 KB
    _Float16* cbf16 = (_Float16*)(cnorm + SDIM);         // 128 KB

    vq_prep<<<SDIM, KDIM, 0, stream>>>(c_sum, c_count, c32, cnorm, cbf16);
    vq_main<<<NVEC / 128, 256, 0, stream>>>(vecs, cbf16, c32, cnorm, out);
    vq_finish<<<1, 1024, 0, stream>>>(out);
}

// Round 4
// 96.517 us; speedup vs baseline: 1.0303x; 1.0303x over previous
//
#include <hip/hip_runtime.h>

// Problem constants
#define NVEC 65536      // B*R*C = 8*16*512
#define KDIM 64
#define SDIM 512

// Output layout (flat float32)
#define Z_OFF       4194304     // NVEC*KDIM
#define LCOMMIT_OFF 4259840
#define LCODE_OFF   4259841
#define E_OFF       4259842

typedef _Float16 half8    __attribute__((ext_vector_type(8)));
typedef float    floatx16 __attribute__((ext_vector_type(16)));

// R11 == R7 restore (measured best: 96.5 us).
// Post-mortem ledger (R10 evidence): per-iteration timed region =
//   ~2x 44us poison fills (harness, untouchable)
// + vq_prep ~1.5us + gaps ~1-2us + vq_main ~5-6us (LDS-read floor 5.1us).
// R10 proved the R7 per-block atomic tail ~= 0 (removing it + adding a
// finish kernel cost +2.9us). R8's prep-fusion killed 4/4 containers.
// So R7's structure is the floor-optimal configuration we can verify.

// ws: c32 [SDIM*KDIM] f32, cnorm [SDIM] f32, cbf16 [SDIM*KDIM*2] f16
//
// cbf16 chunk layout (R4-verified): half index
//   (s>>5)*4096 + p*2048 + q*512 + h*256 + (s&31)*8 + j
// Tile t (128 codewords) = 32 KB contiguous at t*16384 halfs; within the tile
// the layout IS the LDS compute layout -> pure linear 16B DMA staging.

__global__ void vq_prep(const float* __restrict__ c_sum,
                        const float* __restrict__ c_count,
                        float* __restrict__ c32,
                        float* __restrict__ cnorm,
                        _Float16* __restrict__ cbf16,
                        float* __restrict__ out) {
    int s = blockIdx.x;          // 0..511
    int k = threadIdx.x;         // 0..63
    float cnt = c_count[s];
    float inv = 1.0f / fmaxf(cnt, 0.01f);
    float x = c_sum[s * KDIM + k] * inv;
    c32[s * KDIM + k] = x;
    float sq = x * x;
    #pragma unroll
    for (int off = 32; off > 0; off >>= 1)
        sq += __shfl_down(sq, off);
    if (k == 0) cnorm[s] = sq;

    __shared__ _Float16 hb[64], lb[64];
    _Float16 hi = (_Float16)x;
    float hiF = (float)hi;
    _Float16 lo = (_Float16)(x - hiF);
    hb[k] = hi; lb[k] = lo;
    __syncthreads();
    if (k < 16) {
        int p  = k >> 3;
        int qh = k & 7;                       // q*2 + h
        int k0 = (qh >> 1) * 16 + (qh & 1) * 8;
        const _Float16* srcb = (p ? lb : hb) + k0;
        half8 v;
        #pragma unroll
        for (int j = 0; j < 8; ++j) v[j] = srcb[j];
        size_t chunk = ((size_t)(s >> 5) * 16 + p * 8 + qh) * 32 + (s & 31);
        *(half8*)(cbf16 + chunk * 8) = v;
    }
    if (s == 0 && k == 0) {
        out[LCOMMIT_OFF] = 0.0f;
        out[LCODE_OFF]   = 0.0f;
    }
}

// 512 blocks x 256 threads (4 waves, M=32/wave). Double-buffered DMA staging.
__global__ __launch_bounds__(256, 2) void vq_main(const float* __restrict__ vecs,
                                                  const _Float16* __restrict__ cbf16,
                                                  const float* __restrict__ c32,
                                                  const float* __restrict__ cnorm,
                                                  float* __restrict__ out) {
    __shared__ __align__(16) _Float16 cw[2][16384];   // 2 x 32 KB B-tiles
    __shared__ float cnL[512];
    __shared__ float vnL[4][32];
    __shared__ int   zL[4][32];
    __shared__ float esumL[8];

    const int tx   = threadIdx.x;
    const int lane = tx & 63;
    const int w    = tx >> 6;
    const int col  = lane & 31;
    const int h    = lane >> 5;
    const int wvec = (int)blockIdx.x * 128 + w * 32;

    // async DMA of one 32 KB tile: wave w copies bytes [w*8K, w*8K+8K)
    // as 8 instructions x (64 lanes x 16 B). LDS dest = uniform base + lane*16.
    #define DMA_TILE(buf, t)                                                      \
    {                                                                             \
        const _Float16* _src = cbf16 + (size_t)(t) * 16384 + w * 4096 + lane * 8; \
        _Float16* _dst = &cw[buf][w * 4096 + lane * 8];                           \
        _Pragma("unroll")                                                         \
        for (int _i = 0; _i < 8; ++_i)                                            \
            __builtin_amdgcn_global_load_lds(                                     \
                (const __attribute__((address_space(1))) void*)(_src + _i * 512), \
                (__attribute__((address_space(3))) void*)(_dst + _i * 512),       \
                16, 0, 0);                                                        \
    }

    DMA_TILE(0, 0)   // tile 0 in flight during the whole prologue

    // ---- A fragments (hi/lo f16) + vnorm (R4/R5-verified tree) ----
    half8 ahi[4], alo[4];
    float vnp = 0.0f;
    const float* arow = vecs + (size_t)(wvec + col) * KDIM + h * 8;
    #pragma unroll
    for (int q = 0; q < 4; ++q) {
        float4 x0 = *(const float4*)(arow + q * 16);
        float4 x1 = *(const float4*)(arow + q * 16 + 4);
        #define CVT(X, J) { float xx = (X); _Float16 hi5 = (_Float16)xx; \
                            float hf = (float)hi5; ahi[q][J] = hi5; \
                            alo[q][J] = (_Float16)(xx - hf); vnp += xx * xx; }
        CVT(x0.x, 0) CVT(x0.y, 1) CVT(x0.z, 2) CVT(x0.w, 3)
        CVT(x1.x, 4) CVT(x1.y, 5) CVT(x1.z, 6) CVT(x1.w, 7)
        #undef CVT
    }
    vnp += __shfl_xor(vnp, 32);
    if (h == 0) vnL[w][col] = vnp;

    // whole cnorm into LDS once
    cnL[tx]       = cnorm[tx];
    cnL[tx + 256] = cnorm[tx + 256];

    // running argmax of m = -cn/2 + dot (== argmin dist; first-index ties)
    float bm[16];
    int   bi[16];
    #pragma unroll
    for (int r = 0; r < 16; ++r) { bm[r] = -3.4e38f; bi[r] = 0; }

    for (int t = 0; t < 4; ++t) {
        // barrier: (a) all waves past compute on buf[(t+1)&1], (b) compiler's
        // vmcnt(0)+lgkmcnt(0) drain => DMA for tile t landed & visible.
        __syncthreads();
        if (t < 3) DMA_TILE((t + 1) & 1, t + 1)   // in flight across compute(t)

        const _Float16* cwb = cw[t & 1];
        #pragma unroll
        for (int sub = 0; sub < 4; ++sub) {
            const _Float16* bb = cwb + sub * 4096 + lane * 8;
            float ci = -0.5f * cnL[t * 128 + sub * 32 + col];
            floatx16 a0, a1;
            #pragma unroll
            for (int r = 0; r < 16; ++r) { a0[r] = ci; a1[r] = 0.0f; }
            #pragma unroll
            for (int q = 0; q < 4; ++q) {
                half8 bh = *(const half8*)(bb + q * 512);
                half8 bl = *(const half8*)(bb + 2048 + q * 512);
                a0 = __builtin_amdgcn_mfma_f32_32x32x16_f16(ahi[q], bh, a0, 0, 0, 0);
                a1 = __builtin_amdgcn_mfma_f32_32x32x16_f16(alo[q], bh, a1, 0, 0, 0);
                a1 = __builtin_amdgcn_mfma_f32_32x32x16_f16(ahi[q], bl, a1, 0, 0, 0);
            }
            int n = t * 128 + sub * 32 + col;
            #pragma unroll
            for (int r = 0; r < 16; ++r) {
                float m = a0[r] + a1[r];
                if (m > bm[r]) { bm[r] = m; bi[r] = n; }   // strict >, increasing n
            }
        }
    }

    // ---- cross-lane argmax per row (32 cols; xor<=16 stays within h) ----
    #pragma unroll
    for (int r = 0; r < 16; ++r) {
        float v = bm[r]; int i = bi[r];
        #pragma unroll
        for (int off = 16; off > 0; off >>= 1) {
            float ov = __shfl_xor(v, off);
            int   oi = __shfl_xor(i, off);
            if (ov > v || (ov == v && oi < i)) { v = ov; i = oi; }
        }
        bm[r] = v; bi[r] = i;
    }

    if (col == 0) {
        float esum = 0.0f;
        #pragma unroll
        for (int r = 0; r < 16; ++r) {
            int row = (r & 3) + 8 * (r >> 2) + 4 * h;   // C/D row map (verified)
            int vid = wvec + row;
            float err = fmaxf(vnL[w][row] - 2.0f * bm[r], 0.0f);
            out[Z_OFF + vid] = (float)bi[r];
            out[E_OFF + vid] = err;
            zL[w][row] = bi[r];
            esum += err;
        }
        esumL[w * 2 + h] = esum;   // R7: stash partial, no global atomic here
    }

    // ---- vecs_hat gather from c32 (R4-verified), coalesced float4 ----
    #pragma unroll
    for (int it = 0; it < 8; ++it) {
        int row = it * 4 + (lane >> 4);
        int c4  = lane & 15;
        int z   = zL[w][row];
        float4 val = *(const float4*)(c32 + (size_t)z * KDIM + c4 * 4);
        *(float4*)(out + (size_t)(wvec + row) * KDIM + c4 * 4) = val;
    }

    // ---- ONE same-address atomic per block (R7; R10 proved tail ~= 0) ----
    __syncthreads();
    if (tx == 0) {
        float tot = esumL[0] + esumL[1] + esumL[2] + esumL[3]
                  + esumL[4] + esumL[5] + esumL[6] + esumL[7];
        atomicAdd(out + LCOMMIT_OFF, tot * (1.0f / (float)NVEC));
    }
    #undef DMA_TILE
}

extern "C" void kernel_launch(void* const* d_in, const int* in_sizes, int n_in,
                              void* d_out, int out_size, void* d_ws, size_t ws_size,
                              hipStream_t stream) {
    const float* vecs    = (const float*)d_in[0];  // [8,16,512,64]
    const float* c_sum   = (const float*)d_in[1];  // [512,64]
    const float* c_count = (const float*)d_in[2];  // [512]
    float* out = (float*)d_out;

    float*    c32   = (float*)d_ws;                      // 128 KB
    float*    cnorm = c32 + SDIM * KDIM;                 // 2 KB
    _Float16* cbf16 = (_Float16*)(cnorm + SDIM);         // 128 KB

    vq_prep<<<SDIM, KDIM, 0, stream>>>(c_sum, c_count, c32, cnorm, cbf16, out);
    vq_main<<<NVEC / 128, 256, 0, stream>>>(vecs, cbf16, c32, cnorm, out);
}